// Round 9
// baseline (163.252 us; speedup 1.0000x reference)
//
#include <hip/hip_runtime.h>
#include <hip/hip_bf16.h>
#include <math.h>

#define HH 64
#define WW 64
#define HW 4096
#define LDV 136  // Vl row stride in bf16 elems (272 B, 16B-aligned)
#define NSLOT 16

typedef __bf16 bf16x8 __attribute__((ext_vector_type(8)));
typedef float floatx4 __attribute__((ext_vector_type(4)));
typedef unsigned int uint4a __attribute__((ext_vector_type(4)));
typedef unsigned int uint2a __attribute__((ext_vector_type(2)));

// ws layout (byte offsets)
#define WS_Y    0u          // float y[8][128][4096]   16777216 B
#define WS_XTB  16777216u   // bf16 xtb[8][4096][128]   8388608 B
#define WS_WTB  25165824u   // bf16 wtb[9][128][128]     294912 B
#define WS_OWB  25460736u   // bf16 owb[9][32][128]       73728 B
#define WS_PSQ  25534464u   // float[16][256] partial sum/sumsq   16384 B

static __device__ inline ushort f2bf(float f) {
  __hip_bfloat16 h = __float2bfloat16(f);
  return __builtin_bit_cast(ushort, h);
}
static __device__ inline float lo16(unsigned int u) { return __builtin_bit_cast(float, u << 16); }
static __device__ inline float hi16(unsigned int u) { return __builtin_bit_cast(float, u & 0xffff0000u); }

// ---------------- fused prep: x transpose + weight converts + psq zero ------
__global__ __launch_bounds__(256) void k_prep(const float* __restrict__ x,
                                              const float* __restrict__ w,
                                              const float* __restrict__ ow,
                                              ushort* __restrict__ xtb,
                                              ushort* __restrict__ wtb,
                                              ushort* __restrict__ owb,
                                              float* __restrict__ psq) {
  __shared__ float tile[32][33];
  int bid = blockIdx.x;
  if (bid < 4096) {
    int hw0 = (bid & 127) * 32;
    int c0 = ((bid >> 7) & 3) * 32;
    int b = bid >> 9;
    int col = threadIdx.x & 31, row = threadIdx.x >> 5;
    const float* xb = x + ((size_t)b * 128 + c0) * HW + hw0;
#pragma unroll
    for (int i = 0; i < 32; i += 8)
      tile[row + i][col] = xb[(size_t)(row + i) * HW + col];
    __syncthreads();
    int hw = threadIdx.x >> 3, cq = threadIdx.x & 7;
    ushort* xo = xtb + ((size_t)b * HW + hw0) * 128 + c0;
    unsigned int lo = (unsigned int)f2bf(tile[cq * 4 + 0][hw]) |
                      ((unsigned int)f2bf(tile[cq * 4 + 1][hw]) << 16);
    unsigned int hi = (unsigned int)f2bf(tile[cq * 4 + 2][hw]) |
                      ((unsigned int)f2bf(tile[cq * 4 + 3][hw]) << 16);
    uint2a v2 = (uint2a){lo, hi};
    *(uint2a*)(&xo[(size_t)hw * 128 + cq * 4]) = v2;
  } else if (bid < 4096 + 576) {
    int idx = (bid - 4096) * 256 + threadIdx.x;  // < 147456
    int c = idx & 127, o = (idx >> 7) & 127, k = idx >> 14;
    wtb[idx] = f2bf(w[(o * 128 + c) * 9 + k]);
  } else if (bid < 4096 + 720) {
    int j = (bid - 4672) * 256 + threadIdx.x;  // < 36864
    int c = j & 127, o = (j >> 7) & 31, k = j >> 12;
    float v = (o < 27) ? ow[(o * 128 + c) * 9 + k] : 0.f;
    owb[j] = f2bf(v);
  } else {
    for (int i = threadIdx.x; i < NSLOT * 256; i += 256) psq[i] = 0.f;
  }
}

// ---------------- producer/consumer fused deform-conv -----------------------
// grid 1024 (1D), 512 threads = 8 waves. Tile: 128 o x 32 p.
// ROLE SPLIT: waves 0-3 = PRODUCERS (prep/gather/convert/ds_write, the
// VALU+VMEM phase), waves 4-7 = CONSUMERS (ds_read+MFMA). Producers run ONE
// STEP AHEAD: at step k they write slot (k+1)&1 while consumers read slot
// k&1. One __syncthreads per step; producer VALU chain and consumer LDS/MFMA
// chain overlap WITHIN each step -- attacking the measured invariant (R5/R6):
// ~7500 cy/step critical path that neither ILP (R1/R3) nor TLP (R6:
// occupancy 38->74%, dur unchanged) compressed.
// All sync is plain __syncthreads() -- no inline asm (R7/R8 container
// failures correlated with the asm-barrier variant; R1 measured the barrier
// flavor as performance-neutral).
// Hazards: write-slot != read-slot each step; consumer ds_reads of slot s at
// step k complete before the step-k barrier; producers overwrite slot s only
// at step k+1, after that barrier.
// XCD-batch affinity kept (b=bid&7; FETCH-verified 4x in R5).
__global__ __launch_bounds__(512, 4) void k_main(
    const ushort* __restrict__ xtb, const ushort* __restrict__ wtb,
    const ushort* __restrict__ owb, const float* __restrict__ off_b,
    const float* __restrict__ bias, float* __restrict__ y,
    float* __restrict__ psq) {
  __shared__ ushort Vl[2][32 * LDV];  // 2 x 8704 B
  __shared__ float omL[27 * 32];      // 3456 B
  int t = threadIdx.x;
  int lane = t & 63, wv = t >> 6;     // wv 0..7
  bool isProd = (wv < 4);
  int cwv = wv - 4;                   // consumer wave 0..3
  int li = lane & 15, quad = (lane >> 4) & 3;
  int bid = blockIdx.x;
  int b = bid & 7;                    // XCD affinity: XCD = bid % 8 = b
  int hr = bid >> 3;                  // 0..127
  int row = hr >> 1, p0b = (hr & 1) * 32;
  const ushort* xb = xtb + (size_t)b * HW * 128;
  int ch = t & 15;                    // producer: 16-B chunk in pixel row
  int pq = (t >> 4) & 15;             // producer: pixel 0..15 (passes pq, pq+16)

  // ===== phase 1: offset conv -> omL[27][32] =====
  int mi = cwv & 1, ni = cwv >> 1;    // consumer tile roles
  floatx4 oacc = (floatx4){0.f, 0.f, 0.f, 0.f};
  uint4a uA0, uB0, uA1, uB1;          // producer staging, parity pairs
  auto p1load = [&](int k, int p, uint4a& u) {
    int ky = k / 3, kx = k % 3;
    int ry = row - 1 + ky, cx = p0b + p - 1 + kx;
    bool v = (ry >= 0 && ry < HH && cx >= 0 && cx < WW);
    int idx = v ? (ry * WW + cx) : 0;
    uint4a a = *(const uint4a*)(xb + (size_t)idx * 128 + ch * 8);
    u = v ? a : (uint4a){0u, 0u, 0u, 0u};
  };
  auto p1mfma = [&](int k, int buf) {
#pragma unroll
    for (int ks = 0; ks < 4; ++ks) {
      bf16x8 bfrag = __builtin_bit_cast(bf16x8,
          *(const uint4a*)(&Vl[buf][(ni * 16 + li) * LDV + ks * 32 + quad * 8]));
      bf16x8 afrag = __builtin_bit_cast(bf16x8,
          *(const uint4a*)(&owb[(size_t)(k * 32 + mi * 16 + li) * 128 + ks * 32 + quad * 8]));
      oacc = __builtin_amdgcn_mfma_f32_16x16x32_bf16(afrag, bfrag, oacc, 0, 0, 0);
    }
  };

  if (isProd) {
    p1load(0, pq, uA0);
    p1load(0, pq + 16, uB0);
    *(uint4a*)(&Vl[0][pq * LDV + ch * 8]) = uA0;
    *(uint4a*)(&Vl[0][(pq + 16) * LDV + ch * 8]) = uB0;
    p1load(1, pq, uA1);
    p1load(1, pq + 16, uB1);  // data 1 in flight
  }
  __syncthreads();  // Vl[0] (data 0) visible

#define P1STEP(K, UWA, UWB, ULA, ULB)                                         \
  do {                                                                        \
    if (isProd) {                                                             \
      if ((K) < 8) {                                                          \
        *(uint4a*)(&Vl[((K) + 1) & 1][pq * LDV + ch * 8]) = UWA;              \
        *(uint4a*)(&Vl[((K) + 1) & 1][(pq + 16) * LDV + ch * 8]) = UWB;       \
        if ((K) < 7) {                                                        \
          p1load((K) + 2, pq, ULA);                                           \
          p1load((K) + 2, pq + 16, ULB);                                      \
        }                                                                     \
      }                                                                       \
    } else {                                                                  \
      p1mfma((K), (K) & 1);                                                   \
    }                                                                         \
    __syncthreads();                                                          \
  } while (0)

  P1STEP(0, uA1, uB1, uA0, uB0);
  P1STEP(1, uA0, uB0, uA1, uB1);
  P1STEP(2, uA1, uB1, uA0, uB0);
  P1STEP(3, uA0, uB0, uA1, uB1);
  P1STEP(4, uA1, uB1, uA0, uB0);
  P1STEP(5, uA0, uB0, uA1, uB1);
  P1STEP(6, uA1, uB1, uA0, uB0);
  P1STEP(7, uA0, uB0, uA1, uB1);
  P1STEP(8, uA1, uB1, uA0, uB0);
#undef P1STEP

  if (!isProd) {
#pragma unroll
    for (int r = 0; r < 4; ++r) {
      int o = mi * 16 + quad * 4 + r;
      if (o < 27) omL[o * 32 + ni * 16 + li] = oacc[r] + off_b[o];
    }
  }
  __syncthreads();  // omL visible to producers

  // ===== phase 2: deformable sampling (producers) + GEMM (consumers) =====
  floatx4 macc[2][2];
#pragma unroll
  for (int i = 0; i < 2; ++i)
#pragma unroll
    for (int j = 0; j < 2; ++j) macc[i][j] = (floatx4){0.f, 0.f, 0.f, 0.f};

  float wqA0[4], wqB0[4], wqA1[4], wqB1[4];
  int idxA[4], idxB[4];
  uint4a U[8];

  auto prep = [&](int k, int p, float* wq, int* idx4) {
    int ky = k / 3, kx = k % 3;
    float offy = omL[(2 * k) * 32 + p];
    float offx = omL[(2 * k + 1) * 32 + p];
    float mraw = omL[(18 + k) * 32 + p];
    float m = 1.f / (1.f + __expf(-mraw));
    float py = offy + (float)(row - 1 + ky);
    float px = offx + (float)(p0b + p - 1 + kx);
    float y0f = floorf(py), x0f = floorf(px);
    float ly = py - y0f, lx = px - x0f;
    int iy0 = (int)y0f, ix0 = (int)x0f;
    int iy1 = iy0 + 1, ix1 = ix0 + 1;
    float w00 = (1.f - ly) * (1.f - lx) * m, w01 = (1.f - ly) * lx * m;
    float w10 = ly * (1.f - lx) * m, w11 = ly * lx * m;
    if (iy0 < 0 || iy0 > HH - 1) { w00 = 0.f; w01 = 0.f; }
    if (iy1 < 0 || iy1 > HH - 1) { w10 = 0.f; w11 = 0.f; }
    if (ix0 < 0 || ix0 > WW - 1) { w00 = 0.f; w10 = 0.f; }
    if (ix1 < 0 || ix1 > WW - 1) { w01 = 0.f; w11 = 0.f; }
    int cy0 = min(max(iy0, 0), HH - 1), cy1 = min(max(iy1, 0), HH - 1);
    int cx0 = min(max(ix0, 0), WW - 1), cx1 = min(max(ix1, 0), WW - 1);
    idx4[0] = cy0 * WW + cx0;
    idx4[1] = cy0 * WW + cx1;
    idx4[2] = cy1 * WW + cx0;
    idx4[3] = cy1 * WW + cx1;
    wq[0] = w00; wq[1] = w01; wq[2] = w10; wq[3] = w11;
  };
  auto issue = [&]() {
#pragma unroll
    for (int c = 0; c < 4; ++c)
      U[c] = *(const uint4a*)(xb + (size_t)idxA[c] * 128 + ch * 8);
#pragma unroll
    for (int c = 0; c < 4; ++c)
      U[4 + c] = *(const uint4a*)(xb + (size_t)idxB[c] * 128 + ch * 8);
  };
  auto p2mfma = [&](int k, int buf) {
    const ushort* Arow = &wtb[(size_t)(k * 128 + cwv * 32) * 128];
#pragma unroll
    for (int ks = 0; ks < 4; ++ks) {
      bf16x8 b0 = __builtin_bit_cast(bf16x8,
          *(const uint4a*)(&Vl[buf][(li)*LDV + ks * 32 + quad * 8]));
      bf16x8 b1 = __builtin_bit_cast(bf16x8,
          *(const uint4a*)(&Vl[buf][(16 + li) * LDV + ks * 32 + quad * 8]));
      bf16x8 a0 = __builtin_bit_cast(bf16x8,
          *(const uint4a*)(Arow + (size_t)(li)*128 + ks * 32 + quad * 8));
      bf16x8 a1 = __builtin_bit_cast(bf16x8,
          *(const uint4a*)(Arow + (size_t)(16 + li) * 128 + ks * 32 + quad * 8));
      macc[0][0] = __builtin_amdgcn_mfma_f32_16x16x32_bf16(a0, b0, macc[0][0], 0, 0, 0);
      macc[0][1] = __builtin_amdgcn_mfma_f32_16x16x32_bf16(a0, b1, macc[0][1], 0, 0, 0);
      macc[1][0] = __builtin_amdgcn_mfma_f32_16x16x32_bf16(a1, b0, macc[1][0], 0, 0, 0);
      macc[1][1] = __builtin_amdgcn_mfma_f32_16x16x32_bf16(a1, b1, macc[1][1], 0, 0, 0);
    }
  };

#define CONVW(UP, WQ, ROWP, BUF)                                              \
  do {                                                                        \
    uint4a outv;                                                              \
    _Pragma("unroll")                                                         \
    for (int e = 0; e < 4; ++e) {                                             \
      float rlo = WQ[0] * lo16((UP)[0][e]) + WQ[1] * lo16((UP)[1][e]) +       \
                  WQ[2] * lo16((UP)[2][e]) + WQ[3] * lo16((UP)[3][e]);        \
      float rhi = WQ[0] * hi16((UP)[0][e]) + WQ[1] * hi16((UP)[1][e]) +       \
                  WQ[2] * hi16((UP)[2][e]) + WQ[3] * hi16((UP)[3][e]);        \
      outv[e] = (unsigned int)f2bf(rlo) | ((unsigned int)f2bf(rhi) << 16);    \
    }                                                                         \
    *(uint4a*)(&Vl[BUF][(ROWP)*LDV + ch * 8]) = outv;                         \
  } while (0)

  // phase-2 prologue: producers fill Vl[0] with data 0, start data 1 gathers
  if (isProd) {
    prep(0, pq, wqA0, idxA);
    prep(0, pq + 16, wqB0, idxB);
    issue();
    CONVW(U, wqA0, pq, 0);
    CONVW((U + 4), wqB0, pq + 16, 0);
    prep(1, pq, wqA1, idxA);
    prep(1, pq + 16, wqB1, idxB);
    issue();  // data 1 in flight
  }
  __syncthreads();  // Vl[0] (data 0) visible

#define P2STEP(K, WQAW, WQBW, WQAL, WQBL)                                     \
  do {                                                                        \
    if (isProd) {                                                             \
      if ((K) < 8) {                                                          \
        CONVW(U, WQAW, pq, ((K) + 1) & 1);                                    \
        CONVW((U + 4), WQBW, pq + 16, ((K) + 1) & 1);                         \
        if ((K) < 7) {                                                        \
          prep((K) + 2, pq, WQAL, idxA);                                      \
          prep((K) + 2, pq + 16, WQBL, idxB);                                 \
          issue();                                                            \
        }                                                                     \
      }                                                                       \
    } else {                                                                  \
      p2mfma((K), (K) & 1);                                                   \
    }                                                                         \
    __syncthreads();                                                          \
  } while (0)

  P2STEP(0, wqA1, wqB1, wqA0, wqB0);
  P2STEP(1, wqA0, wqB0, wqA1, wqB1);
  P2STEP(2, wqA1, wqB1, wqA0, wqB0);
  P2STEP(3, wqA0, wqB0, wqA1, wqB1);
  P2STEP(4, wqA1, wqB1, wqA0, wqB0);
  P2STEP(5, wqA0, wqB0, wqA1, wqB1);
  P2STEP(6, wqA1, wqB1, wqA0, wqB0);
  P2STEP(7, wqA0, wqB0, wqA1, wqB1);
  P2STEP(8, wqA1, wqB1, wqA0, wqB0);
#undef P2STEP
#undef CONVW

  // ===== epilogue (consumers): bias + y store + BN partial stats =====
  if (!isProd) {
    int slot = bid & (NSLOT - 1);
#pragma unroll
    for (int ot = 0; ot < 2; ++ot)
#pragma unroll
      for (int r = 0; r < 4; ++r) {
        int o = cwv * 32 + ot * 16 + quad * 4 + r;
        float v0 = macc[ot][0][r] + bias[o];
        float v1 = macc[ot][1][r] + bias[o];
        y[((size_t)(b * 128 + o)) * HW + row * 64 + p0b + li] = v0;
        y[((size_t)(b * 128 + o)) * HW + row * 64 + p0b + 16 + li] = v1;
        float s = v0 + v1, q = v0 * v0 + v1 * v1;
#pragma unroll
        for (int m = 1; m < 16; m <<= 1) {
          s += __shfl_xor(s, m, 64);
          q += __shfl_xor(q, m, 64);
        }
        if (li == 0) {
          atomicAdd(&psq[slot * 256 + o], s);
          atomicAdd(&psq[slot * 256 + 128 + o], q);
        }
      }
  }
}

// ---------------- normalize + ReLU (scale/shift computed inline) ------------
// Same XCD-batch decode (b = blk % 8) so y[b] is read on the XCD whose L2
// holds it dirty from k_main.
__global__ __launch_bounds__(256) void k_norm(const float* __restrict__ y,
                                              const float* __restrict__ psq,
                                              const float* __restrict__ gamma,
                                              const float* __restrict__ beta,
                                              float* __restrict__ out) {
  int blk = blockIdx.x;
  int b = blk & 7;             // XCD affinity matches k_main writer
  int o = (blk >> 3) & 127;
  int qseg = blk >> 10;        // quarter of the (b,o) plane
  float s = 0.f, q = 0.f;
#pragma unroll
  for (int j = 0; j < NSLOT; ++j) {
    s += psq[j * 256 + o];
    q += psq[j * 256 + 128 + o];
  }
  float mean = s * (1.f / 32768.f);
  float var = q * (1.f / 32768.f) - mean * mean;
  float scale = gamma[o] * rsqrtf(var + 1e-5f);
  float shift = beta[o] - mean * scale;
  int i4 = (b * 128 + o) * 1024 + qseg * 256 + threadIdx.x;
  float4 v = ((const float4*)y)[i4];
  float4 r;
  r.x = fmaxf(v.x * scale + shift, 0.f);
  r.y = fmaxf(v.y * scale + shift, 0.f);
  r.z = fmaxf(v.z * scale + shift, 0.f);
  r.w = fmaxf(v.w * scale + shift, 0.f);
  ((float4*)out)[i4] = r;
}

extern "C" void kernel_launch(void* const* d_in, const int* in_sizes, int n_in,
                              void* d_out, int out_size, void* d_ws, size_t ws_size,
                              hipStream_t stream) {
  const float* x     = (const float*)d_in[0];
  const float* off_w = (const float*)d_in[1];
  const float* off_b = (const float*)d_in[2];
  const float* w     = (const float*)d_in[3];
  const float* bias  = (const float*)d_in[4];
  const float* gamma = (const float*)d_in[5];
  const float* beta  = (const float*)d_in[6];
  float* out = (float*)d_out;
  char* ws = (char*)d_ws;

  float* y    = (float*)(ws + WS_Y);
  ushort* xtb = (ushort*)(ws + WS_XTB);
  ushort* wtb = (ushort*)(ws + WS_WTB);
  ushort* owb = (ushort*)(ws + WS_OWB);
  float* psq  = (float*)(ws + WS_PSQ);

  k_prep<<<4817, 256, 0, stream>>>(x, w, off_w, xtb, wtb, owb, psq);
  k_main<<<1024, 512, 0, stream>>>(xtb, wtb, owb, off_b, bias, y, psq);
  k_norm<<<4096, 256, 0, stream>>>(y, psq, gamma, beta, out);
}

// Round 10
// 161.815 us; speedup vs baseline: 1.0089x; 1.0089x over previous
//
#include <hip/hip_runtime.h>
#include <hip/hip_bf16.h>
#include <math.h>

#define HH 64
#define WW 64
#define HW 4096
#define LDV 136  // padded row stride in bf16 elems (272 B): 2-way-free banks
#define NSLOT 16

typedef __bf16 bf16x8 __attribute__((ext_vector_type(8)));
typedef float floatx4 __attribute__((ext_vector_type(4)));
typedef unsigned int uint4a __attribute__((ext_vector_type(4)));
typedef unsigned int uint2a __attribute__((ext_vector_type(2)));

// ws layout (byte offsets)
#define WS_Y    0u          // float y[8][128][4096]   16777216 B
#define WS_XTB  16777216u   // bf16 xtb[8][4096][128]   8388608 B
#define WS_WTB  25165824u   // bf16 wtb[9][128][128]     294912 B
#define WS_OWB  25460736u   // bf16 owb[9][32][128]       73728 B
#define WS_PSQ  25534464u   // float[16][256]             16384 B
#define WS_OM   25550848u   // float om[8][27][4096]    3538944 B

static __device__ inline ushort f2bf(float f) {
  __hip_bfloat16 h = __float2bfloat16(f);
  return __builtin_bit_cast(ushort, h);
}
static __device__ inline float lo16(unsigned int u) { return __builtin_bit_cast(float, u << 16); }
static __device__ inline float hi16(unsigned int u) { return __builtin_bit_cast(float, u & 0xffff0000u); }

// ---------------- fused prep: x transpose + weight converts + psq zero ------
__global__ __launch_bounds__(256) void k_prep(const float* __restrict__ x,
                                              const float* __restrict__ w,
                                              const float* __restrict__ ow,
                                              ushort* __restrict__ xtb,
                                              ushort* __restrict__ wtb,
                                              ushort* __restrict__ owb,
                                              float* __restrict__ psq) {
  __shared__ float tile[32][33];
  int bid = blockIdx.x;
  if (bid < 4096) {
    int hw0 = (bid & 127) * 32;
    int c0 = ((bid >> 7) & 3) * 32;
    int b = bid >> 9;
    int col = threadIdx.x & 31, row = threadIdx.x >> 5;
    const float* xb = x + ((size_t)b * 128 + c0) * HW + hw0;
#pragma unroll
    for (int i = 0; i < 32; i += 8)
      tile[row + i][col] = xb[(size_t)(row + i) * HW + col];
    __syncthreads();
    int hw = threadIdx.x >> 3, cq = threadIdx.x & 7;
    ushort* xo = xtb + ((size_t)b * HW + hw0) * 128 + c0;
    unsigned int lo = (unsigned int)f2bf(tile[cq * 4 + 0][hw]) |
                      ((unsigned int)f2bf(tile[cq * 4 + 1][hw]) << 16);
    unsigned int hi = (unsigned int)f2bf(tile[cq * 4 + 2][hw]) |
                      ((unsigned int)f2bf(tile[cq * 4 + 3][hw]) << 16);
    uint2a v2 = (uint2a){lo, hi};
    *(uint2a*)(&xo[(size_t)hw * 128 + cq * 4]) = v2;
  } else if (bid < 4096 + 576) {
    int idx = (bid - 4096) * 256 + threadIdx.x;  // < 147456
    int c = idx & 127, o = (idx >> 7) & 127, k = idx >> 14;
    wtb[idx] = f2bf(w[(o * 128 + c) * 9 + k]);
  } else if (bid < 4096 + 720) {
    int j = (bid - 4672) * 256 + threadIdx.x;  // < 36864
    int c = j & 127, o = (j >> 7) & 31, k = j >> 12;
    float v = (o < 27) ? ow[(o * 128 + c) * 9 + k] : 0.f;
    owb[j] = f2bf(v);
  } else {
    for (int i = threadIdx.x; i < NSLOT * 256; i += 256) psq[i] = 0.f;
  }
}

// ---------------- k_off: dense 3x3 offset conv, ONE barrier -----------------
// grid 512 (row 0..63 x batch, XCD-affine b=bid&7), 256 thr = 4 waves.
// Stage rows row-1..row+1 (full width, 128 ch, LDV-padded) -> one barrier ->
// 9 taps x 4 k-slices x 2 o-tiles MFMA per wave straight from LDS. Replaces
// k_main's phase 1, which paid 9 lockstep barrier-steps (~35 us at the
// measured ~3.9 us/step invariant) for 3% of the FLOPs.
__global__ __launch_bounds__(256) void k_off(const ushort* __restrict__ xtb,
                                             const ushort* __restrict__ owb,
                                             const float* __restrict__ off_b,
                                             float* __restrict__ om) {
  __shared__ ushort S[3 * 64 * LDV];  // 52224 B
  int t = threadIdx.x;
  int lane = t & 63, wv = t >> 6;
  int li = lane & 15, quad = (lane >> 4) & 3;
  int bid = blockIdx.x;
  int b = bid & 7;        // XCD affinity
  int row = bid >> 3;     // 0..63
  const ushort* xb = xtb + (size_t)b * HW * 128;

  // stage 3 rows (zeros for out-of-image rows)
#pragma unroll
  for (int i = 0; i < 12; ++i) {
    int idx = t + i * 256;          // 0..3071
    int rr = idx >> 10;             // row 0..2
    int rem = idx & 1023;
    int col = rem >> 4, chunk = rem & 15;
    int gy = row - 1 + rr;
    uint4a v = (uint4a){0u, 0u, 0u, 0u};
    if (gy >= 0 && gy < HH)
      v = *(const uint4a*)(xb + ((size_t)(gy * WW + col)) * 128 + chunk * 8);
    *(uint4a*)(&S[(rr * 64 + col) * LDV + chunk * 8]) = v;
  }
  __syncthreads();

  int pxbase = wv * 16;
  floatx4 acc0 = (floatx4){0.f, 0.f, 0.f, 0.f};
  floatx4 acc1 = (floatx4){0.f, 0.f, 0.f, 0.f};
  for (int k = 0; k < 9; ++k) {
    int ky = k / 3, kx = k % 3;
    int c = pxbase + li - 1 + kx;
    bool ok = (c >= 0 && c < WW);
    int cc = min(max(c, 0), WW - 1);
#pragma unroll
    for (int ks = 0; ks < 4; ++ks) {
      uint4a bv = *(const uint4a*)(&S[(ky * 64 + cc) * LDV + ks * 32 + quad * 8]);
      bv = ok ? bv : (uint4a){0u, 0u, 0u, 0u};
      bf16x8 bf = __builtin_bit_cast(bf16x8, bv);
      bf16x8 a0 = __builtin_bit_cast(bf16x8,
          *(const uint4a*)(&owb[(size_t)(k * 32 + li) * 128 + ks * 32 + quad * 8]));
      bf16x8 a1 = __builtin_bit_cast(bf16x8,
          *(const uint4a*)(&owb[(size_t)(k * 32 + 16 + li) * 128 + ks * 32 + quad * 8]));
      acc0 = __builtin_amdgcn_mfma_f32_16x16x32_bf16(a0, bf, acc0, 0, 0, 0);
      acc1 = __builtin_amdgcn_mfma_f32_16x16x32_bf16(a1, bf, acc1, 0, 0, 0);
    }
  }
  int px = row * WW + pxbase + li;
#pragma unroll
  for (int r = 0; r < 4; ++r) {
    int o0 = quad * 4 + r;
    om[((size_t)b * 27 + o0) * HW + px] = acc0[r] + off_b[o0];
    int o1 = 16 + quad * 4 + r;
    if (o1 < 27)
      om[((size_t)b * 27 + o1) * HW + px] = acc1[r] + off_b[o1];
  }
}

// ---------------- k_deform: sampling + main GEMM + BN partials --------------
// R0's proven phase-2 loop verbatim (70.5us structure, plain __syncthreads),
// prefixed by a one-time omL load from global om, with R5's fused-stats
// epilogue. 9 barrier-steps instead of k_main's 18.
__global__ __launch_bounds__(256) void k_deform(
    const ushort* __restrict__ xtb, const ushort* __restrict__ wtb,
    const float* __restrict__ om, const float* __restrict__ bias,
    float* __restrict__ y, float* __restrict__ psq) {
  __shared__ ushort Vl[2][32 * LDV];  // 2 x 8704 B
  __shared__ float omL[27 * 32];      // 3456 B
  int t = threadIdx.x;
  int lane = t & 63, wv = t >> 6;
  int li = lane & 15, quad = lane >> 4;
  int bid = blockIdx.x;
  int b = bid & 7;          // XCD affinity
  int hr = bid >> 3;        // 0..127
  int row = hr >> 1, p0b = (hr & 1) * 32;
  const ushort* xb = xtb + (size_t)b * HW * 128;
  int ch = t & 15;   // 16-B chunk within the 256-B pixel row
  int pq = t >> 4;   // pixel within pass (0..15); passes: pq and pq+16

  // load omL[27][32] for this tile (off_b already applied in k_off)
  for (int i = t; i < 27 * 32; i += 256) {
    int o = i >> 5, p = i & 31;
    omL[o * 32 + p] = om[((size_t)b * 27 + o) * HW + row * 64 + p0b + p];
  }
  __syncthreads();

  floatx4 macc[2][2];
#pragma unroll
  for (int i = 0; i < 2; ++i)
#pragma unroll
    for (int j = 0; j < 2; ++j) macc[i][j] = (floatx4){0.f, 0.f, 0.f, 0.f};

  float wqA[4], wqB[4];
  int idxA[4], idxB[4];
  uint4a u[8];

  auto prep = [&](int k, int p, float* wq, int* idx4) {
    int ky = k / 3, kx = k % 3;
    float offy = omL[(2 * k) * 32 + p];
    float offx = omL[(2 * k + 1) * 32 + p];
    float mraw = omL[(18 + k) * 32 + p];
    float m = 1.f / (1.f + __expf(-mraw));
    float py = offy + (float)(row - 1 + ky);
    float px = offx + (float)(p0b + p - 1 + kx);
    float y0f = floorf(py), x0f = floorf(px);
    float ly = py - y0f, lx = px - x0f;
    int iy0 = (int)y0f, ix0 = (int)x0f;
    int iy1 = iy0 + 1, ix1 = ix0 + 1;
    float w00 = (1.f - ly) * (1.f - lx) * m, w01 = (1.f - ly) * lx * m;
    float w10 = ly * (1.f - lx) * m, w11 = ly * lx * m;
    if (iy0 < 0 || iy0 > HH - 1) { w00 = 0.f; w01 = 0.f; }
    if (iy1 < 0 || iy1 > HH - 1) { w10 = 0.f; w11 = 0.f; }
    if (ix0 < 0 || ix0 > WW - 1) { w00 = 0.f; w10 = 0.f; }
    if (ix1 < 0 || ix1 > WW - 1) { w01 = 0.f; w11 = 0.f; }
    int cy0 = min(max(iy0, 0), HH - 1), cy1 = min(max(iy1, 0), HH - 1);
    int cx0 = min(max(ix0, 0), WW - 1), cx1 = min(max(ix1, 0), WW - 1);
    idx4[0] = cy0 * WW + cx0;
    idx4[1] = cy0 * WW + cx1;
    idx4[2] = cy1 * WW + cx0;
    idx4[3] = cy1 * WW + cx1;
    wq[0] = w00; wq[1] = w01; wq[2] = w10; wq[3] = w11;
  };
  auto issue = [&]() {
#pragma unroll
    for (int c = 0; c < 4; ++c)
      u[c] = *(const uint4a*)(xb + (size_t)idxA[c] * 128 + ch * 8);
#pragma unroll
    for (int c = 0; c < 4; ++c)
      u[4 + c] = *(const uint4a*)(xb + (size_t)idxB[c] * 128 + ch * 8);
  };

  prep(0, pq, wqA, idxA);
  prep(0, pq + 16, wqB, idxB);
  issue();
  for (int k = 0; k < 9; ++k) {
    // convert this k's gathers (fp32 math) -> Vl[k&1]
    {
      uint4a outv;
#pragma unroll
      for (int e = 0; e < 4; ++e) {
        float rlo = wqA[0] * lo16(u[0][e]) + wqA[1] * lo16(u[1][e]) +
                    wqA[2] * lo16(u[2][e]) + wqA[3] * lo16(u[3][e]);
        float rhi = wqA[0] * hi16(u[0][e]) + wqA[1] * hi16(u[1][e]) +
                    wqA[2] * hi16(u[2][e]) + wqA[3] * hi16(u[3][e]);
        outv[e] = (unsigned int)f2bf(rlo) | ((unsigned int)f2bf(rhi) << 16);
      }
      *(uint4a*)(&Vl[k & 1][pq * LDV + ch * 8]) = outv;
    }
    {
      uint4a outv;
#pragma unroll
      for (int e = 0; e < 4; ++e) {
        float rlo = wqB[0] * lo16(u[4][e]) + wqB[1] * lo16(u[5][e]) +
                    wqB[2] * lo16(u[6][e]) + wqB[3] * lo16(u[7][e]);
        float rhi = wqB[0] * hi16(u[4][e]) + wqB[1] * hi16(u[5][e]) +
                    wqB[2] * hi16(u[6][e]) + wqB[3] * hi16(u[7][e]);
        outv[e] = (unsigned int)f2bf(rlo) | ((unsigned int)f2bf(rhi) << 16);
      }
      *(uint4a*)(&Vl[k & 1][(pq + 16) * LDV + ch * 8]) = outv;
    }
    if (k < 8) {  // prefetch k+1: gathers fly during barrier wait + MFMA
      prep(k + 1, pq, wqA, idxA);
      prep(k + 1, pq + 16, wqB, idxB);
      issue();
    }
    __syncthreads();  // Vl[k&1] writes visible
    const ushort* Arow = &wtb[(size_t)(k * 128 + wv * 32) * 128];
#pragma unroll
    for (int ks = 0; ks < 4; ++ks) {
      bf16x8 b0 = __builtin_bit_cast(bf16x8,
          *(const uint4a*)(&Vl[k & 1][(li)*LDV + ks * 32 + quad * 8]));
      bf16x8 b1 = __builtin_bit_cast(bf16x8,
          *(const uint4a*)(&Vl[k & 1][(16 + li) * LDV + ks * 32 + quad * 8]));
      bf16x8 a0 = __builtin_bit_cast(bf16x8,
          *(const uint4a*)(Arow + (size_t)(li)*128 + ks * 32 + quad * 8));
      bf16x8 a1 = __builtin_bit_cast(bf16x8,
          *(const uint4a*)(Arow + (size_t)(16 + li) * 128 + ks * 32 + quad * 8));
      macc[0][0] = __builtin_amdgcn_mfma_f32_16x16x32_bf16(a0, b0, macc[0][0], 0, 0, 0);
      macc[0][1] = __builtin_amdgcn_mfma_f32_16x16x32_bf16(a0, b1, macc[0][1], 0, 0, 0);
      macc[1][0] = __builtin_amdgcn_mfma_f32_16x16x32_bf16(a1, b0, macc[1][0], 0, 0, 0);
      macc[1][1] = __builtin_amdgcn_mfma_f32_16x16x32_bf16(a1, b1, macc[1][1], 0, 0, 0);
    }
  }

  // ===== epilogue: bias + y store + BN partial stats (fused k_stats) =====
  int slot = bid & (NSLOT - 1);
#pragma unroll
  for (int ot = 0; ot < 2; ++ot)
#pragma unroll
    for (int r = 0; r < 4; ++r) {
      int o = wv * 32 + ot * 16 + quad * 4 + r;
      float v0 = macc[ot][0][r] + bias[o];
      float v1 = macc[ot][1][r] + bias[o];
      y[((size_t)(b * 128 + o)) * HW + row * 64 + p0b + li] = v0;
      y[((size_t)(b * 128 + o)) * HW + row * 64 + p0b + 16 + li] = v1;
      float s = v0 + v1, q = v0 * v0 + v1 * v1;
#pragma unroll
      for (int m = 1; m < 16; m <<= 1) {
        s += __shfl_xor(s, m, 64);
        q += __shfl_xor(q, m, 64);
      }
      if (li == 0) {
        atomicAdd(&psq[slot * 256 + o], s);
        atomicAdd(&psq[slot * 256 + 128 + o], q);
      }
    }
}

// ---------------- normalize + ReLU (scale/shift computed inline) ------------
__global__ __launch_bounds__(256) void k_norm(const float* __restrict__ y,
                                              const float* __restrict__ psq,
                                              const float* __restrict__ gamma,
                                              const float* __restrict__ beta,
                                              float* __restrict__ out) {
  int blk = blockIdx.x;
  int b = blk & 7;             // XCD affinity matches k_deform writer
  int o = (blk >> 3) & 127;
  int qseg = blk >> 10;        // quarter of the (b,o) plane
  float s = 0.f, q = 0.f;
#pragma unroll
  for (int j = 0; j < NSLOT; ++j) {
    s += psq[j * 256 + o];
    q += psq[j * 256 + 128 + o];
  }
  float mean = s * (1.f / 32768.f);
  float var = q * (1.f / 32768.f) - mean * mean;
  float scale = gamma[o] * rsqrtf(var + 1e-5f);
  float shift = beta[o] - mean * scale;
  int i4 = (b * 128 + o) * 1024 + qseg * 256 + threadIdx.x;
  float4 v = ((const float4*)y)[i4];
  float4 r;
  r.x = fmaxf(v.x * scale + shift, 0.f);
  r.y = fmaxf(v.y * scale + shift, 0.f);
  r.z = fmaxf(v.z * scale + shift, 0.f);
  r.w = fmaxf(v.w * scale + shift, 0.f);
  ((float4*)out)[i4] = r;
}

extern "C" void kernel_launch(void* const* d_in, const int* in_sizes, int n_in,
                              void* d_out, int out_size, void* d_ws, size_t ws_size,
                              hipStream_t stream) {
  const float* x     = (const float*)d_in[0];
  const float* off_w = (const float*)d_in[1];
  const float* off_b = (const float*)d_in[2];
  const float* w     = (const float*)d_in[3];
  const float* bias  = (const float*)d_in[4];
  const float* gamma = (const float*)d_in[5];
  const float* beta  = (const float*)d_in[6];
  float* out = (float*)d_out;
  char* ws = (char*)d_ws;

  float* y    = (float*)(ws + WS_Y);
  ushort* xtb = (ushort*)(ws + WS_XTB);
  ushort* wtb = (ushort*)(ws + WS_WTB);
  ushort* owb = (ushort*)(ws + WS_OWB);
  float* psq  = (float*)(ws + WS_PSQ);
  float* om   = (float*)(ws + WS_OM);

  k_prep<<<4817, 256, 0, stream>>>(x, w, off_w, xtb, wtb, owb, psq);
  k_off<<<512, 256, 0, stream>>>(xtb, owb, off_b, om);
  k_deform<<<1024, 256, 0, stream>>>(xtb, wtb, om, bias, y, psq);
  k_norm<<<4096, 256, 0, stream>>>(y, psq, gamma, beta, out);
}